// Round 1
// baseline (602.005 us; speedup 1.0000x reference)
//
#include <hip/hip_runtime.h>

// Multi-level sparse hash encoding (instant-NGP style), forward only.
// B = 2^20 points, D=3, L=16 levels, E=2 features, tables (16, 16385, 2) f32.
// One thread per (point, level); 8-corner trilinear gather-accumulate.

#define B_POINTS (1 << 20)
#define N_LEVELS 16
#define TAB_STRIDE (2 * (16384 + 1))   // floats per level in emb

// floor(16 * gf^l) with gf = float32 exp chain (rounds above 2^(1/3)):
__constant__ int   cRES[N_LEVELS]  = {16, 20, 25, 32, 40, 50, 64, 80,
                                      101, 128, 161, 203, 256, 322, 406, 512};
__constant__ float cHALF[N_LEVELS] = {8.f, 10.f, 12.5f, 16.f, 20.f, 25.f, 32.f, 40.f,
                                      50.5f, 64.f, 80.5f, 101.5f, 128.f, 161.f, 203.f, 256.f};
// sentinel row index == n_encs per level (row is zeroed in emb)
__constant__ int   cSENT[N_LEVELS] = {4096, 8000, 15625, 16384, 16384, 16384, 16384, 16384,
                                      16384, 16384, 16384, 16384, 16384, 16384, 16384, 16384};

__global__ __launch_bounds__(256)
void hashenc_fwd(const float* __restrict__ x,
                 const float* __restrict__ emb,
                 float* __restrict__ out)
{
    const int tid = blockIdx.x * 256 + threadIdx.x;
    const int l = tid & 15;
    const int b = tid >> 4;

    const float x0 = x[b * 3 + 0];
    const float x1 = x[b * 3 + 1];
    const float x2 = x[b * 3 + 2];

    const int   R    = cRES[l];
    const float half = cHALF[l];
    const int   sent = cSENT[l];
    const bool  direct = (l < 3);

    const float xs0 = (x0 + 1.0f) * half - 0.5f;
    const float xs1 = (x1 + 1.0f) * half - 0.5f;
    const float xs2 = (x2 + 1.0f) * half - 0.5f;
    const float fl0 = floorf(xs0), fl1 = floorf(xs1), fl2 = floorf(xs2);
    const float f0 = xs0 - fl0, f1 = xs1 - fl1, f2 = xs2 - fl2;
    const float g0 = 1.0f - f0, g1 = 1.0f - f1, g2 = 1.0f - f2;
    const int i0 = (int)fl0, i1 = (int)fl1, i2 = (int)fl2;

    const float* __restrict__ tab = emb + (size_t)l * TAB_STRIDE;

    float acc0 = 0.0f, acc1 = 0.0f;
#pragma unroll
    for (int k = 0; k < 8; ++k) {
        const int o0 = (k >> 2) & 1, o1 = (k >> 1) & 1, o2 = k & 1;
        const int c0 = i0 + o0, c1 = i1 + o1, c2 = i2 + o2;
        const float w = (o0 ? f0 : g0) * (o1 ? f1 : g1) * (o2 ? f2 : g2);
        const bool valid = (c0 >= 0) & (c0 < R) &
                           (c1 >= 0) & (c1 < R) &
                           (c2 >= 0) & (c2 < R);
        int id;
        if (direct) {
            id = (c0 * R + c1) * R + c2;
        } else {
            const unsigned h = (unsigned)c0 * 1u
                             ^ (unsigned)c1 * 2654435761u
                             ^ (unsigned)c2 * 805459861u;
            id = (int)(h & 16383u);
        }
        id = valid ? id : sent;
        const float2 e = *(const float2*)(tab + (size_t)id * 2);
        acc0 = fmaf(e.x, w, acc0);
        acc1 = fmaf(e.y, w, acc1);
    }

    // out[b][l][e] : tid-th float2, fully coalesced
    ((float2*)out)[tid] = make_float2(acc0, acc1);
}

extern "C" void kernel_launch(void* const* d_in, const int* in_sizes, int n_in,
                              void* d_out, int out_size, void* d_ws, size_t ws_size,
                              hipStream_t stream) {
    const float* x   = (const float*)d_in[0];   // (B, 3) f32
    const float* emb = (const float*)d_in[1];   // (16, 16385, 2) f32
    float* out = (float*)d_out;                 // (B, 16, 2) f32

    const int total = B_POINTS * N_LEVELS;      // 16,777,216 threads
    hashenc_fwd<<<total / 256, 256, 0, stream>>>(x, emb, out);
}